// Round 8
// baseline (146.094 us; speedup 1.0000x reference)
//
#include <hip/hip_runtime.h>

// Problem dims
#define NB   4
#define CIN  256
#define MID  64
#define HW   4096
#define NBLK 128   // n-tiles of 32 rows

typedef __attribute__((ext_vector_type(8))) short bfrag8;   // 8 bf16 (4 VGPR) MFMA operand
typedef __attribute__((ext_vector_type(4))) float facc4;    // MFMA accumulator

// Workspace layout (bytes), total ~21.4 MB
constexpr size_t OFF_FGHT  = 0;           // [B][4096][128] f32 (f,g)
constexpr size_t OFF_FHI   = 8388608;     // [B][4096][64] bf16
constexpr size_t OFF_FLO   = 10485760;    // [B][4096][64] bf16
constexpr size_t OFF_W2HI  = 12582912;    // [B][256][64] bf16
constexpr size_t OFF_W2LO  = 12713984;    // [B][256][64] bf16
constexpr size_t OFF_MPART = 12845056;    // [B][128][64][64] f32
constexpr size_t OFF_TPART = 21233664;    // [B][128][64] f32
constexpr size_t OFF_FGVUP = 21364736;    // [B][16][128] f32
constexpr size_t OFF_NSQP  = 21397504;    // [B][16] f32

__device__ __forceinline__ unsigned short f2bf(float f) {
    union { float f; unsigned u; } v; v.f = f;
    unsigned r = v.u + 0x7FFF + ((v.u >> 16) & 1);  // RNE
    return (unsigned short)(r >> 16);
}
__device__ __forceinline__ float bf2f(unsigned short h) {
    union { unsigned u; float f; } v; v.u = ((unsigned)h) << 16;
    return v.f;
}
__device__ __forceinline__ void split_bf(float v, unsigned short& hi, unsigned short& lo) {
    hi = f2bf(v);
    lo = f2bf(v - bf2f(hi));
}

// K1 (mega): per block: 32 n x all 192 o. BN-fold inline; split-bf16 MFMA;
// epilogue: fghT f32 (f,g), fhi/flo bf16 (f), t-partials + M-partials from in-LDS g,h.
__launch_bounds__(512)
__global__ void k_fgh2(const float* __restrict__ x,
                       const float* __restrict__ Wf, const float* __restrict__ bf,
                       const float* __restrict__ gaf, const float* __restrict__ btf,
                       const float* __restrict__ mef, const float* __restrict__ vaf,
                       const float* __restrict__ Wg, const float* __restrict__ bg,
                       const float* __restrict__ gag, const float* __restrict__ btg,
                       const float* __restrict__ meg, const float* __restrict__ vag,
                       const float* __restrict__ Wh, const float* __restrict__ bh,
                       const float* __restrict__ v0,
                       float* __restrict__ fghT,
                       unsigned short* __restrict__ fhi, unsigned short* __restrict__ flo,
                       float* __restrict__ tpart, float* __restrict__ mpart) {
    __shared__ float invs[192], beffs[192];
    __shared__ unsigned short xh[32][72], xl[32][72];
    __shared__ char wbuf[55296];   // wh[192][72], wl[192][72] ushort; aliased in epilogue
    unsigned short (*wh)[72] = (unsigned short(*)[72])wbuf;
    unsigned short (*wl)[72] = (unsigned short(*)[72])(wbuf + 192 * 72 * 2);

    const int nb = blockIdx.x, b = blockIdx.y;
    const int n0 = nb * 32;
    const int tid = threadIdx.x, l = tid & 63, w = tid >> 6;  // 8 waves
    const int wo = w >> 1, wn = w & 1;                        // 4 o-groups(48) x 2 n-halves(16)
    const int lr = l & 15, lk = l >> 4;

    if (tid < 192) {
        float inv, sh;
        if (tid < 64)       { inv = gaf[tid] * rsqrtf(vaf[tid] + 1e-5f);
                              sh = bf[tid] * inv + btf[tid] - mef[tid] * inv; }
        else if (tid < 128) { int o = tid - 64; inv = gag[o] * rsqrtf(vag[o] + 1e-5f);
                              sh = bg[o] * inv + btg[o] - meg[o] * inv; }
        else                { inv = 1.0f; sh = bh[tid - 128]; }
        invs[tid] = inv; beffs[tid] = sh;
    }
    __syncthreads();

    facc4 acc[3];
    #pragma unroll
    for (int j = 0; j < 3; ++j) acc[j] = (facc4){0.f, 0.f, 0.f, 0.f};

    for (int kc = 0; kc < 4; ++kc) {
        const int c0 = kc * 64;
        {   // stage x chunk [64c][32n] f32 -> xh/xl [n][c]
            const int c = tid >> 3, n4 = (tid & 7) * 4;
            const float* xr = x + ((size_t)(b * CIN + c0 + c)) * HW + n0 + n4;
            float4 v = *(const float4*)xr;
            #pragma unroll
            for (int i = 0; i < 4; ++i) {
                unsigned short hi, lo; split_bf((&v.x)[i], hi, lo);
                xh[n4 + i][c] = hi; xl[n4 + i][c] = lo;
            }
        }
        {   // stage w chunk [192o][64c] with inline BN fold
            #pragma unroll
            for (int k = 0; k < 3; ++k) {
                const int id = tid + k * 512;
                const int orow = id >> 3, cs = id & 7;
                const float* wrow;
                if (orow < 64)       wrow = Wf + orow * CIN;
                else if (orow < 128) wrow = Wg + (orow - 64) * CIN;
                else                 wrow = Wh + (orow - 128) * CIN;
                const float inv = invs[orow];
                float4 a4 = *(const float4*)(wrow + c0 + cs * 8);
                float4 b4 = *(const float4*)(wrow + c0 + cs * 8 + 4);
                unsigned short h8[8] __attribute__((aligned(16)));
                unsigned short l8[8] __attribute__((aligned(16)));
                #pragma unroll
                for (int i = 0; i < 4; ++i) split_bf((&a4.x)[i] * inv, h8[i], l8[i]);
                #pragma unroll
                for (int i = 0; i < 4; ++i) split_bf((&b4.x)[i] * inv, h8[4 + i], l8[4 + i]);
                *(bfrag8*)&wh[orow][cs * 8] = *(const bfrag8*)h8;
                *(bfrag8*)&wl[orow][cs * 8] = *(const bfrag8*)l8;
            }
        }
        __syncthreads();
        #pragma unroll
        for (int ks = 0; ks < 2; ++ks) {
            bfrag8 ah = *(const bfrag8*)&xh[wn * 16 + lr][ks * 32 + lk * 8];
            bfrag8 al = *(const bfrag8*)&xl[wn * 16 + lr][ks * 32 + lk * 8];
            #pragma unroll
            for (int so = 0; so < 3; ++so) {
                bfrag8 bh8 = *(const bfrag8*)&wh[wo * 48 + so * 16 + lr][ks * 32 + lk * 8];
                bfrag8 bl8 = *(const bfrag8*)&wl[wo * 48 + so * 16 + lr][ks * 32 + lk * 8];
                acc[so] = __builtin_amdgcn_mfma_f32_16x16x32_bf16(ah, bh8, acc[so], 0, 0, 0);
                acc[so] = __builtin_amdgcn_mfma_f32_16x16x32_bf16(ah, bl8, acc[so], 0, 0, 0);
                acc[so] = __builtin_amdgcn_mfma_f32_16x16x32_bf16(al, bh8, acc[so], 0, 0, 0);
            }
        }
        __syncthreads();
    }

    // ---- epilogue (wbuf aliased: g,h tile + reduce scratch) ----
    float (*mls)[136] = (float(*)[136])wbuf;              // [32 n][128 c'] 17.4 KB
    float (*tred)[64] = (float(*)[64])(wbuf + 17408);     // [8][64] 2 KB
    float* v0ls       = (float*)(wbuf + 17408 + 2048);    // [32]

    #pragma unroll
    for (int so = 0; so < 3; ++so) {
        const int o = wo * 48 + so * 16 + lr;
        const float bias = beffs[o];
        const bool rl = (o < 128);   // relu on f,g only
        #pragma unroll
        for (int r = 0; r < 4; ++r) {
            const int nn = wn * 16 + lk * 4 + r;
            const int n = n0 + nn;
            float v = acc[so][r] + bias;
            if (rl) v = fmaxf(v, 0.0f);
            if (o < 128) fghT[((size_t)(b * HW) + n) * 128 + o] = v;
            if (o < 64) {
                unsigned short hi, lo; split_bf(v, hi, lo);
                fhi[((size_t)(b * HW) + n) * MID + o] = hi;
                flo[((size_t)(b * HW) + n) * MID + o] = lo;
            }
            if (o >= 64) mls[nn][o - 64] = v;   // g cols 0..63, h cols 64..127
        }
    }
    if (tid < 32) v0ls[tid] = v0[(size_t)b * HW + n0 + tid];
    __syncthreads();

    {   // t partials
        const int c = tid & 63, ng = tid >> 6;
        float tp = 0.f;
        #pragma unroll
        for (int i = 0; i < 4; ++i) {
            const int nn = ng * 4 + i;
            tp = fmaf(mls[nn][c], v0ls[nn], tp);
        }
        tred[ng][c] = tp;
    }
    __syncthreads();
    if (tid < 64) {
        float s = 0.f;
        #pragma unroll
        for (int g = 0; g < 8; ++g) s += tred[g][tid];
        tpart[((size_t)(b * NBLK) + nb) * 64 + tid] = s;
    }
    {   // M partials: mpart[b][nb][cp][cc]
        const int tcp = tid >> 4, tc = tid & 15;
        const int cp = tcp * 2, cc = tc * 4;
        float macc[2][4];
        #pragma unroll
        for (int i = 0; i < 2; ++i)
            #pragma unroll
            for (int j = 0; j < 4; ++j) macc[i][j] = 0.f;
        for (int nn = 0; nn < 32; ++nn) {
            const float g0 = mls[nn][cp], g1 = mls[nn][cp + 1];
            const float h0 = mls[nn][64 + cc + 0], h1 = mls[nn][64 + cc + 1];
            const float h2 = mls[nn][64 + cc + 2], h3 = mls[nn][64 + cc + 3];
            macc[0][0] = fmaf(g0, h0, macc[0][0]); macc[0][1] = fmaf(g0, h1, macc[0][1]);
            macc[0][2] = fmaf(g0, h2, macc[0][2]); macc[0][3] = fmaf(g0, h3, macc[0][3]);
            macc[1][0] = fmaf(g1, h0, macc[1][0]); macc[1][1] = fmaf(g1, h1, macc[1][1]);
            macc[1][2] = fmaf(g1, h2, macc[1][2]); macc[1][3] = fmaf(g1, h3, macc[1][3]);
        }
        const size_t mpb = ((size_t)(b * NBLK) + nb) * 4096;
        *(float4*)&mpart[mpb + (size_t)(cp + 0) * 64 + cc] =
            make_float4(macc[0][0], macc[0][1], macc[0][2], macc[0][3]);
        *(float4*)&mpart[mpb + (size_t)(cp + 1) * 64 + cc] =
            make_float4(macc[1][0], macc[1][1], macc[1][2], macc[1][3]);
    }
}

// K2: reduce tpart -> t (in LDS); vu = f.t per n; per-block partials of nsq and fgvu.
__launch_bounds__(256)
__global__ void k_vfg(const float* __restrict__ fghT, const float* __restrict__ tpart,
                      float* __restrict__ fgvu_part, float* __restrict__ nsq_part) {
    __shared__ float tred4[4][64];
    __shared__ float ts[64];
    __shared__ float vuls[256];
    __shared__ float red2[8][128];
    __shared__ float rs[4];
    const int chunk = blockIdx.x, b = blockIdx.y, n0 = chunk * 256;
    const int tid = threadIdx.x;
    {   // reduce t partials: 128 nb
        const int c = tid & 63, grp = tid >> 6;
        float s = 0.f;
        #pragma unroll 8
        for (int i = 0; i < 32; ++i)
            s += tpart[((size_t)(b * NBLK) + grp * 32 + i) * 64 + c];
        tred4[grp][c] = s;
    }
    __syncthreads();
    if (tid < 64) ts[tid] = tred4[0][tid] + tred4[1][tid] + tred4[2][tid] + tred4[3][tid];
    __syncthreads();
    // phase 1: vu for 256 n (4 lanes per n)
    const int nl = tid >> 2, q = tid & 3;
    float mynsq = 0.f;
    for (int ps = 0; ps < 4; ++ps) {
        const int n = n0 + ps * 64 + nl;
        const float* p = fghT + ((size_t)(b * HW) + n) * 128 + q * 16;
        float a = 0.f;
        #pragma unroll
        for (int u = 0; u < 4; ++u) {
            float4 fv = *(const float4*)(p + u * 4);
            a = fmaf(fv.x, ts[q * 16 + u * 4 + 0], a);
            a = fmaf(fv.y, ts[q * 16 + u * 4 + 1], a);
            a = fmaf(fv.z, ts[q * 16 + u * 4 + 2], a);
            a = fmaf(fv.w, ts[q * 16 + u * 4 + 3], a);
        }
        a += __shfl_xor(a, 1);
        a += __shfl_xor(a, 2);
        if (q == 0) { vuls[ps * 64 + nl] = a; mynsq += a * a; }
    }
    {
        float s = mynsq;
        #pragma unroll
        for (int off = 32; off > 0; off >>= 1) s += __shfl_down(s, off);
        if ((tid & 63) == 0) rs[tid >> 6] = s;
        __syncthreads();
        if (tid == 0) nsq_part[b * 16 + chunk] = rs[0] + rs[1] + rs[2] + rs[3];
    }
    // phase 2: fgvu partials
    const int rq = tid & 31, ng2 = tid >> 5;
    float a2[4] = {0.f, 0.f, 0.f, 0.f};
    for (int it = 0; it < 32; ++it) {
        const int ni = ng2 + 8 * it;
        float4 fv = *(const float4*)(fghT + ((size_t)(b * HW) + n0 + ni) * 128 + rq * 4);
        const float vv = vuls[ni];
        a2[0] = fmaf(fv.x, vv, a2[0]); a2[1] = fmaf(fv.y, vv, a2[1]);
        a2[2] = fmaf(fv.z, vv, a2[2]); a2[3] = fmaf(fv.w, vv, a2[3]);
    }
    #pragma unroll
    for (int i = 0; i < 4; ++i) red2[ng2][rq * 4 + i] = a2[i];
    __syncthreads();
    if (tid < 128) {
        float s = 0.f;
        #pragma unroll
        for (int g = 0; g < 8; ++g) s += red2[g][tid];
        fgvu_part[(size_t)(b * 16 + chunk) * 128 + tid] = s;
    }
}

// K3: reduce mpart + fgvu/nsq partials; s; w2 = (1/s) Wv M^T  (hi/lo bf16)
__launch_bounds__(256)
__global__ void k_w2s(const float* __restrict__ Wv, const float* __restrict__ mpart,
                      const float* __restrict__ fgvu_part, const float* __restrict__ nsq_part,
                      unsigned short* __restrict__ w2hi, unsigned short* __restrict__ w2lo) {
    __shared__ float Mc[8][64];
    __shared__ float svs;
    const int cp0 = blockIdx.x * 8, b = blockIdx.y;
    const int tid = threadIdx.x;
    {   // reduce 128 nb-partials for rows cp0..cp0+7
        const int c = tid & 63;
        const int r0 = tid >> 6, r1 = r0 + 4;
        float s0 = 0.f, s1 = 0.f;
        for (int nb = 0; nb < NBLK; ++nb) {
            const size_t base = ((size_t)(b * NBLK) + nb) * 4096;
            s0 += mpart[base + (size_t)(cp0 + r0) * 64 + c];
            s1 += mpart[base + (size_t)(cp0 + r1) * 64 + c];
        }
        Mc[r0][c] = s0;
        Mc[r1][c] = s1;
    }
    if (tid < 64) {
        float fv = 0.f, gv = 0.f, ns = 0.f;
        #pragma unroll
        for (int ch = 0; ch < 16; ++ch) {
            fv += fgvu_part[(size_t)(b * 16 + ch) * 128 + tid];
            gv += fgvu_part[(size_t)(b * 16 + ch) * 128 + 64 + tid];
        }
        if (tid < 16) ns = nsq_part[b * 16 + tid];
        float a = fv * gv;
        #pragma unroll
        for (int off = 32; off > 0; off >>= 1) {
            a += __shfl_down(a, off);
            ns += __shfl_down(ns, off);
        }
        if (tid == 0) svs = a / ns;
    }
    __syncthreads();
    const float inv_s = 1.0f / svs;
    const int o = tid;
    float wv[64];
    #pragma unroll
    for (int u = 0; u < 16; ++u) {
        float4 w4 = *(const float4*)(Wv + o * MID + u * 4);
        wv[u * 4 + 0] = w4.x; wv[u * 4 + 1] = w4.y; wv[u * 4 + 2] = w4.z; wv[u * 4 + 3] = w4.w;
    }
    unsigned short rh[8] __attribute__((aligned(16)));
    unsigned short rl[8] __attribute__((aligned(16)));
    #pragma unroll
    for (int j = 0; j < 8; ++j) {
        float a = 0.f;
        #pragma unroll
        for (int c = 0; c < 64; ++c) a = fmaf(wv[c], Mc[j][c], a);
        split_bf(a * inv_s, rh[j], rl[j]);
    }
    const size_t base = ((size_t)(b * CIN) + o) * MID + cp0;
    *(bfrag8*)(w2hi + base) = *(const bfrag8*)rh;
    *(bfrag8*)(w2lo + base) = *(const bfrag8*)rl;
}

// K4: out[b][o][n] = x + bv[o] + sum_cp w2[o][cp] f[n][cp]   via split-bf16 MFMA, D[o][n]
__launch_bounds__(256)
__global__ void k_out(const float* __restrict__ x,
                      const unsigned short* __restrict__ fhi, const unsigned short* __restrict__ flo,
                      const unsigned short* __restrict__ w2hi, const unsigned short* __restrict__ w2lo,
                      const float* __restrict__ bv, float* __restrict__ out) {
    __shared__ unsigned short fh[64][72], fl[64][72], wh[64][72], wl[64][72];
    const int n0 = blockIdx.x * 64;
    const int o0 = blockIdx.y * 64;
    const int b  = blockIdx.z;
    const int tid = threadIdx.x, l = tid & 63, w = tid >> 6;
    const int wo = w >> 1, wn = w & 1;
    const int lr = l & 15, lk = l >> 4;
    #pragma unroll
    for (int i = 0; i < 2; ++i) {
        int ch = tid + i * 256;
        int row = ch >> 3, cs = ch & 7;
        const size_t fsrc = ((size_t)(b * HW) + n0 + row) * MID + cs * 8;
        const size_t wsrc = ((size_t)(b * CIN) + o0 + row) * MID + cs * 8;
        *(bfrag8*)&fh[row][cs * 8] = *(const bfrag8*)(fhi + fsrc);
        *(bfrag8*)&fl[row][cs * 8] = *(const bfrag8*)(flo + fsrc);
        *(bfrag8*)&wh[row][cs * 8] = *(const bfrag8*)(w2hi + wsrc);
        *(bfrag8*)&wl[row][cs * 8] = *(const bfrag8*)(w2lo + wsrc);
    }
    __syncthreads();
    facc4 acc[2][2];   // [so][sn]
    #pragma unroll
    for (int i = 0; i < 2; ++i)
        #pragma unroll
        for (int j = 0; j < 2; ++j) acc[i][j] = (facc4){0.f, 0.f, 0.f, 0.f};
    #pragma unroll
    for (int ks = 0; ks < 2; ++ks) {
        bfrag8 ah[2], al[2], bh[2], bl[2];
        #pragma unroll
        for (int s = 0; s < 2; ++s) {
            ah[s] = *(const bfrag8*)&wh[wo * 32 + s * 16 + lr][ks * 32 + lk * 8];
            al[s] = *(const bfrag8*)&wl[wo * 32 + s * 16 + lr][ks * 32 + lk * 8];
            bh[s] = *(const bfrag8*)&fh[wn * 32 + s * 16 + lr][ks * 32 + lk * 8];
            bl[s] = *(const bfrag8*)&fl[wn * 32 + s * 16 + lr][ks * 32 + lk * 8];
        }
        #pragma unroll
        for (int so = 0; so < 2; ++so)
            #pragma unroll
            for (int sn = 0; sn < 2; ++sn) {
                acc[so][sn] = __builtin_amdgcn_mfma_f32_16x16x32_bf16(ah[so], bh[sn], acc[so][sn], 0, 0, 0);
                acc[so][sn] = __builtin_amdgcn_mfma_f32_16x16x32_bf16(ah[so], bl[sn], acc[so][sn], 0, 0, 0);
                acc[so][sn] = __builtin_amdgcn_mfma_f32_16x16x32_bf16(al[so], bh[sn], acc[so][sn], 0, 0, 0);
            }
    }
    #pragma unroll
    for (int so = 0; so < 2; ++so)
        #pragma unroll
        for (int r = 0; r < 4; ++r) {
            const int o = o0 + wo * 32 + so * 16 + lk * 4 + r;
            const float bias = bv[o];
            #pragma unroll
            for (int sn = 0; sn < 2; ++sn) {
                const int n = n0 + wn * 32 + sn * 16 + lr;
                const size_t idx = ((size_t)(b * CIN) + o) * HW + n;
                out[idx] = x[idx] + bias + acc[so][sn][r];
            }
        }
}

extern "C" void kernel_launch(void* const* d_in, const int* in_sizes, int n_in,
                              void* d_out, int out_size, void* d_ws, size_t ws_size,
                              hipStream_t stream) {
    const float* x   = (const float*)d_in[0];
    const float* Wf  = (const float*)d_in[1];
    const float* bf  = (const float*)d_in[2];
    const float* gaf = (const float*)d_in[3];
    const float* bef = (const float*)d_in[4];
    const float* mef = (const float*)d_in[5];
    const float* vaf = (const float*)d_in[6];
    const float* Wg  = (const float*)d_in[7];
    const float* bg  = (const float*)d_in[8];
    const float* gag = (const float*)d_in[9];
    const float* beg = (const float*)d_in[10];
    const float* meg = (const float*)d_in[11];
    const float* vag = (const float*)d_in[12];
    const float* Wh  = (const float*)d_in[13];
    const float* bh  = (const float*)d_in[14];
    const float* Wv  = (const float*)d_in[15];
    const float* bv  = (const float*)d_in[16];
    const float* v0  = (const float*)d_in[17];
    float* out = (float*)d_out;
    char* ws = (char*)d_ws;

    float*          fghT = (float*)(ws + OFF_FGHT);
    unsigned short* fhi  = (unsigned short*)(ws + OFF_FHI);
    unsigned short* flo  = (unsigned short*)(ws + OFF_FLO);
    unsigned short* w2hi = (unsigned short*)(ws + OFF_W2HI);
    unsigned short* w2lo = (unsigned short*)(ws + OFF_W2LO);
    float*          mpart= (float*)(ws + OFF_MPART);
    float*          tpart= (float*)(ws + OFF_TPART);
    float*          fgvup= (float*)(ws + OFF_FGVUP);
    float*          nsqp = (float*)(ws + OFF_NSQP);

    k_fgh2<<<dim3(NBLK, NB), 512, 0, stream>>>(x, Wf, bf, gaf, bef, mef, vaf,
                                               Wg, bg, gag, beg, meg, vag, Wh, bh,
                                               v0, fghT, fhi, flo, tpart, mpart);
    k_vfg <<<dim3(16, NB), 256, 0, stream>>>(fghT, tpart, fgvup, nsqp);
    k_w2s <<<dim3(8, NB), 256, 0, stream>>>(Wv, mpart, fgvup, nsqp, w2hi, w2lo);
    k_out <<<dim3(HW / 64, CIN / 64, NB), 256, 0, stream>>>(x, fhi, flo, w2hi, w2lo, bv, out);
}